// Round 1
// baseline (156.754 us; speedup 1.0000x reference)
//
#include <hip/hip_runtime.h>

#define NSEED 256

__device__ __forceinline__ float fast_exp(float x) {
  // e^x = 2^(x * log2(e)); v_exp_f32 computes 2^x
  return __builtin_amdgcn_exp2f(x * 1.4426950408889634f);
}
__device__ __forceinline__ float sigf(float x) {
  return 1.0f / (1.0f + fast_exp(-x));
}

// Precompute per-seed params into ws: [sx, sy, c/sc, sn/sc, -sn*sc, c*sc, h, g]
__global__ void seed_params_kernel(const float* __restrict__ seeds,
                                   const float* __restrict__ h_raw,
                                   const float* __restrict__ theta,
                                   const float* __restrict__ a_raw,
                                   const float* __restrict__ seed_gates,
                                   float* __restrict__ P) {
  int s = threadIdx.x;
  if (s >= NSEED) return;
  float sx = seeds[2 * s], sy = seeds[2 * s + 1];
  float th = theta[s];
  float c = cosf(th), sn = sinf(th);
  float sc = expf(a_raw[s]);
  float inv_sc = 1.0f / sc;
  float h = 0.5f + 1.5f * sigf(h_raw[s]);       // H_MIN + (H_MAX-H_MIN)*sigmoid
  float g = sigf(seed_gates[s]);
  P[8 * s + 0] = sx;
  P[8 * s + 1] = sy;
  P[8 * s + 2] = c * inv_sc;
  P[8 * s + 3] = sn * inv_sc;
  P[8 * s + 4] = -sn * sc;
  P[8 * s + 5] = c * sc;
  P[8 * s + 6] = h;
  P[8 * s + 7] = g;
}

__global__ __launch_bounds__(256) void voronoi_kernel(
    const float* __restrict__ uv, const float* __restrict__ P,
    const float* __restrict__ w_raw, const float* __restrict__ seeds,
    float* __restrict__ out, int nq) {
  const int q = blockIdx.x * 256 + threadIdx.x;
  if (q >= nq) return;
  const float2 uvq = ((const float2*)uv)[q];
  const float u = uvq.x, v = uvq.y;
  const float4* __restrict__ P4 = (const float4*)P;

  // ---- Pass A: top-8 selection (sorted ascending) + indices of 2 nearest ----
  float dk0 = 3e38f, dk1 = 3e38f, dk2 = 3e38f, dk3 = 3e38f;
  float dk4 = 3e38f, dk5 = 3e38f, dk6 = 3e38f, dk7 = 3e38f;
  int i0 = 0, i1 = 0;

#pragma unroll 4
  for (int s = 0; s < NSEED; ++s) {
    float4 pa = P4[2 * s];      // sx, sy, a11, a12   (uniform address -> s_load)
    float4 pb = P4[2 * s + 1];  // a21, a22, h, g
    float dx = u - pa.x, dy = v - pa.y;
    float xp = fmaf(pa.z, dx, pa.w * dy);
    float yp = fmaf(pb.x, dx, pb.y * dy);
    float d = __builtin_amdgcn_sqrtf(fmaf(xp, xp, fmaf(yp, yp, 1e-8f)));
    // index tracking with OLD dk0/dk1 (strict < matches top_k tie-break)
    bool c0 = d < dk0;
    bool c1 = d < dk1;
    int sh = c0 ? i0 : s;
    i1 = c1 ? sh : i1;
    i0 = c0 ? s : i0;
    // predicated sorted insert: new dk_j = clamp(d, dk_{j-1}, dk_j), high->low
    dk7 = fminf(fmaxf(d, dk6), dk7);
    dk6 = fminf(fmaxf(d, dk5), dk6);
    dk5 = fminf(fmaxf(d, dk4), dk5);
    dk4 = fminf(fmaxf(d, dk3), dk4);
    dk3 = fminf(fmaxf(d, dk2), dk3);
    dk2 = fminf(fmaxf(d, dk1), dk2);
    dk1 = fminf(fmaxf(d, dk0), dk1);
    dk0 = fminf(d, dk0);
  }

  const float d1 = dk0, d3 = dk2;

  // ---- Pass B: full softmax sums with known max (d1) -> no rescaling ----
  const float KB = 72.13475204444817f;  // log2(e)/BETA, BETA=0.02
  float S1 = 0.f, S2 = 0.f, Sh = 0.f, Sg = 0.f;
#pragma unroll 4
  for (int s = 0; s < NSEED; ++s) {
    float4 pa = P4[2 * s];
    float4 pb = P4[2 * s + 1];
    float dx = u - pa.x, dy = v - pa.y;
    float xp = fmaf(pa.z, dx, pa.w * dy);
    float yp = fmaf(pb.x, dx, pb.y * dy);
    float d = __builtin_amdgcn_sqrtf(fmaf(xp, xp, fmaf(yp, yp, 1e-8f)));
    float e = __builtin_amdgcn_exp2f((d1 - d) * KB);  // exp((d1-d)/beta) <= 1
    S1 += e;
    S2 = fmaf(e, e, S2);
    Sh = fmaf(e, pb.z, Sh);
    Sg = fmaf(e, pb.w, Sg);
  }

  // ---- Epilogue ----
  // w_pair = W[i0,i1], W = W_MIN + (wmax-W_MIN)*0.5*(sig(wr01/5)+sig(wr10/5))
  float ax = seeds[2 * i0], ay = seeds[2 * i0 + 1];
  float bx = seeds[2 * i1], by = seeds[2 * i1 + 1];
  float pdx = ax - bx, pdy = ay - by;
  float pd = __builtin_amdgcn_sqrtf(fmaf(pdx, pdx, pdy * pdy));
  float wmax = fmaxf(0.8f * pd, 0.005f + 1e-8f);
  float wr01 = w_raw[(i0 << 8) + i1];
  float wr10 = w_raw[(i1 << 8) + i0];
  float w_pair = 0.005f + (wmax - 0.005f) * 0.5f * (sigf(wr01 * 0.2f) + sigf(wr10 * 0.2f));

  // k_eff = 1/(sum p^2 + EPS) = S1^2 / (S2 + EPS*S1^2)
  float s1sq = S1 * S1;
  float keff = s1sq / fmaf(1e-8f, s1sq, S2);
  float bonus = 0.15f * sigf((keff - 3.0f) * (1.0f / 0.35f));

  // triple = 0.15 * exp(-t^1.5), t = (d3-d1)/(w_pair+EPS)
  float t = (d3 - d1) / (w_pair + 1e-8f);
  float t15 = t * __builtin_amdgcn_sqrtf(t);
  float triple = 0.15f * fast_exp(-t15);

  float w_eff = w_pair * (1.0f + bonus + triple);

  // softmin over b_j = 0.5*(dk_j - d1), j=1..7:
  // sdist = b1 - tau*ln(sum_j exp((b1-b_j)/tau)),  (b1-b_j)/tau = (dk1-dk_j)*0.5/tau
  const float HT = 360.6737602222409f;  // 0.5/tau * log2(e), tau=0.002
  float acc = 1.0f;  // j=1 term
  acc += __builtin_amdgcn_exp2f((dk1 - dk2) * HT);
  acc += __builtin_amdgcn_exp2f((dk1 - dk3) * HT);
  acc += __builtin_amdgcn_exp2f((dk1 - dk4) * HT);
  acc += __builtin_amdgcn_exp2f((dk1 - dk5) * HT);
  acc += __builtin_amdgcn_exp2f((dk1 - dk6) * HT);
  acc += __builtin_amdgcn_exp2f((dk1 - dk7) * HT);
  float b1 = 0.5f * (dk1 - d1);
  float sdist = b1 - 0.002f * 0.6931471805599453f * __builtin_amdgcn_logf(acc);

  float wall = sigf((0.5f * w_eff - sdist) * 50.0f);  // /BETA
  float invS1 = 1.0f / S1;
  out[q] = wall * (Sg * invS1) * (Sh * invS1);
}

extern "C" void kernel_launch(void* const* d_in, const int* in_sizes, int n_in,
                              void* d_out, int out_size, void* d_ws, size_t ws_size,
                              hipStream_t stream) {
  (void)in_sizes;
  (void)n_in;
  (void)ws_size;
  const float* uv = (const float*)d_in[0];
  const float* seeds = (const float*)d_in[1];
  const float* w_raw = (const float*)d_in[2];
  const float* h_raw = (const float*)d_in[3];
  const float* theta = (const float*)d_in[4];
  const float* a_raw = (const float*)d_in[5];
  const float* gates = (const float*)d_in[6];
  float* out = (float*)d_out;
  float* P = (float*)d_ws;  // 256 seeds * 8 floats = 8 KB

  seed_params_kernel<<<1, 256, 0, stream>>>(seeds, h_raw, theta, a_raw, gates, P);
  int nq = out_size;
  int grid = (nq + 255) / 256;
  voronoi_kernel<<<grid, 256, 0, stream>>>(uv, P, w_raw, seeds, out, nq);
}

// Round 2
// 125.274 us; speedup vs baseline: 1.2513x; 1.2513x over previous
//
#include <hip/hip_runtime.h>

#define NSEED 256

__device__ __forceinline__ float fast_exp(float x) {
  // e^x = 2^(x * log2(e)); v_exp_f32 computes 2^x
  return __builtin_amdgcn_exp2f(x * 1.4426950408889634f);
}
__device__ __forceinline__ float sigf(float x) {
  return 1.0f / (1.0f + fast_exp(-x));
}
__device__ __forceinline__ float med3(float x, float lo, float hi) {
  // == min(max(x,lo),hi) when lo<=hi (always true for our sorted slots)
  return __builtin_amdgcn_fmed3f(x, lo, hi);
}

__global__ __launch_bounds__(256) void voronoi_kernel(
    const float* __restrict__ uv, const float* __restrict__ seeds,
    const float* __restrict__ w_raw, const float* __restrict__ h_raw,
    const float* __restrict__ theta, const float* __restrict__ a_raw,
    const float* __restrict__ seed_gates, float* __restrict__ out, int nq) {
  // Per-seed params: [sx, sy, c/sc, sn/sc] [-sn*sc, c*sc, h, g]
  __shared__ float4 Plds[NSEED * 2];

  {
    // Per-block prologue: one thread per seed (block=256). Redundant across
    // blocks but trivial (256 lanes of libm per block).
    int s = threadIdx.x;
    float sx = seeds[2 * s], sy = seeds[2 * s + 1];
    float th = theta[s];
    float c = cosf(th), sn = sinf(th);
    float sc = expf(a_raw[s]);
    float inv = 1.0f / sc;
    float h = 0.5f + 1.5f * sigf(h_raw[s]);  // H_MIN + (H_MAX-H_MIN)*sigmoid
    float g = sigf(seed_gates[s]);
    Plds[2 * s] = make_float4(sx, sy, c * inv, sn * inv);
    Plds[2 * s + 1] = make_float4(-sn * sc, c * sc, h, g);
  }
  __syncthreads();

  const int q = blockIdx.x * 256 + threadIdx.x;
  if (q >= nq) return;
  const float2 uvq = ((const float2*)uv)[q];
  const float u = uvq.x, v = uvq.y;

  // ---- Pass A: top-8 on squared distance (sorted ascending) + 2 indices ----
  float dk0 = 3e38f, dk1 = 3e38f, dk2 = 3e38f, dk3 = 3e38f;
  float dk4 = 3e38f, dk5 = 3e38f, dk6 = 3e38f, dk7 = 3e38f;
  int i0 = 0, i1 = 0;

#pragma unroll 8
  for (int s = 0; s < NSEED; ++s) {
    float4 pa = Plds[2 * s];      // broadcast ds_read_b128
    float4 pb = Plds[2 * s + 1];
    float dx = u - pa.x, dy = v - pa.y;
    float xp = fmaf(pa.z, dx, pa.w * dy);
    float yp = fmaf(pb.x, dx, pb.y * dy);
    float d2 = fmaf(xp, xp, fmaf(yp, yp, 1e-8f));
    // index tracking with OLD dk0/dk1 (strict < matches top_k tie-break)
    bool c0 = d2 < dk0;
    bool c1 = d2 < dk1;
    int sh = c0 ? i0 : s;
    i1 = c1 ? sh : i1;
    i0 = c0 ? s : i0;
    // predicated sorted insert, high->low, med3 = clamp
    dk7 = med3(d2, dk6, dk7);
    dk6 = med3(d2, dk5, dk6);
    dk5 = med3(d2, dk4, dk5);
    dk4 = med3(d2, dk3, dk4);
    dk3 = med3(d2, dk2, dk3);
    dk2 = med3(d2, dk1, dk2);
    dk1 = med3(d2, dk0, dk1);
    dk0 = fminf(d2, dk0);
  }

  // sqrt the kept 8 (matches pass-B's sqrt of the identical d2 bit pattern)
  dk0 = __builtin_amdgcn_sqrtf(dk0);
  dk1 = __builtin_amdgcn_sqrtf(dk1);
  dk2 = __builtin_amdgcn_sqrtf(dk2);
  dk3 = __builtin_amdgcn_sqrtf(dk3);
  dk4 = __builtin_amdgcn_sqrtf(dk4);
  dk5 = __builtin_amdgcn_sqrtf(dk5);
  dk6 = __builtin_amdgcn_sqrtf(dk6);
  dk7 = __builtin_amdgcn_sqrtf(dk7);

  const float d1 = dk0, d3 = dk2;

  // ---- Pass B: full softmax sums with known max (d1) -> no rescaling ----
  const float KB = 72.13475204444817f;   // log2(e)/BETA, BETA=0.02
  const float C1 = d1 * KB;              // exp arg = fma(-KB, d, C1)
  float S1 = 0.f, S2 = 0.f, Sh = 0.f, Sg = 0.f;
#pragma unroll 8
  for (int s = 0; s < NSEED; ++s) {
    float4 pa = Plds[2 * s];
    float4 pb = Plds[2 * s + 1];
    float dx = u - pa.x, dy = v - pa.y;
    float xp = fmaf(pa.z, dx, pa.w * dy);
    float yp = fmaf(pb.x, dx, pb.y * dy);
    float d2 = fmaf(xp, xp, fmaf(yp, yp, 1e-8f));
    float d = __builtin_amdgcn_sqrtf(d2);
    float e = __builtin_amdgcn_exp2f(fmaf(-KB, d, C1));  // exp((d1-d)/beta)
    S1 += e;
    S2 = fmaf(e, e, S2);
    Sh = fmaf(e, pb.z, Sh);
    Sg = fmaf(e, pb.w, Sg);
  }

  // ---- Epilogue ----
  // w_pair = W[i0,i1]; W = W_MIN + (wmax-W_MIN)*0.5*(sig(wr01/5)+sig(wr10/5))
  float4 pi0 = Plds[2 * i0];
  float4 pi1 = Plds[2 * i1];
  float pdx = pi0.x - pi1.x, pdy = pi0.y - pi1.y;
  float pd = __builtin_amdgcn_sqrtf(fmaf(pdx, pdx, pdy * pdy));
  float wmax = fmaxf(0.8f * pd, 0.005f + 1e-8f);
  float wr01 = w_raw[(i0 << 8) + i1];
  float wr10 = w_raw[(i1 << 8) + i0];
  float w_pair = 0.005f + (wmax - 0.005f) * 0.5f * (sigf(wr01 * 0.2f) + sigf(wr10 * 0.2f));

  // k_eff = 1/(sum p^2 + EPS) = S1^2 / (S2 + EPS*S1^2)
  float s1sq = S1 * S1;
  float keff = s1sq / fmaf(1e-8f, s1sq, S2);
  float bonus = 0.15f * sigf((keff - 3.0f) * (1.0f / 0.35f));

  // triple = 0.15 * exp(-t^1.5), t = (d3-d1)/(w_pair+EPS)
  float t = (d3 - d1) / (w_pair + 1e-8f);
  float t15 = t * __builtin_amdgcn_sqrtf(t);
  float triple = 0.15f * fast_exp(-t15);

  float w_eff = w_pair * (1.0f + bonus + triple);

  // softmin over b_j = 0.5*(dk_j - d1), j=1..7:
  // sdist = b1 - tau*ln(sum_j exp((b1-b_j)/tau)), (b1-b_j)/tau = (dk1-dk_j)*0.5/tau
  const float HT = 360.6737602222409f;  // 0.5/tau * log2(e), tau=0.002
  float acc = 1.0f;  // j=1 term
  acc += __builtin_amdgcn_exp2f((dk1 - dk2) * HT);
  acc += __builtin_amdgcn_exp2f((dk1 - dk3) * HT);
  acc += __builtin_amdgcn_exp2f((dk1 - dk4) * HT);
  acc += __builtin_amdgcn_exp2f((dk1 - dk5) * HT);
  acc += __builtin_amdgcn_exp2f((dk1 - dk6) * HT);
  acc += __builtin_amdgcn_exp2f((dk1 - dk7) * HT);
  float b1 = 0.5f * (dk1 - d1);
  float sdist = b1 - 0.002f * 0.6931471805599453f * __builtin_amdgcn_logf(acc);

  float wall = sigf((0.5f * w_eff - sdist) * 50.0f);  // /BETA
  float invS1 = 1.0f / S1;
  out[q] = wall * (Sg * invS1) * (Sh * invS1);
}

extern "C" void kernel_launch(void* const* d_in, const int* in_sizes, int n_in,
                              void* d_out, int out_size, void* d_ws, size_t ws_size,
                              hipStream_t stream) {
  (void)in_sizes;
  (void)n_in;
  (void)d_ws;
  (void)ws_size;
  const float* uv = (const float*)d_in[0];
  const float* seeds = (const float*)d_in[1];
  const float* w_raw = (const float*)d_in[2];
  const float* h_raw = (const float*)d_in[3];
  const float* theta = (const float*)d_in[4];
  const float* a_raw = (const float*)d_in[5];
  const float* gates = (const float*)d_in[6];
  float* out = (float*)d_out;

  int nq = out_size;
  int grid = (nq + 255) / 256;
  voronoi_kernel<<<grid, 256, 0, stream>>>(uv, seeds, w_raw, h_raw, theta,
                                           a_raw, gates, out, nq);
}

// Round 3
// 124.820 us; speedup vs baseline: 1.2558x; 1.0036x over previous
//
#include <hip/hip_runtime.h>

#define NSEED 256

typedef float v2f __attribute__((ext_vector_type(2)));
typedef float v4f __attribute__((ext_vector_type(4)));

__device__ __forceinline__ float fast_exp(float x) {
  return __builtin_amdgcn_exp2f(x * 1.4426950408889634f);  // e^x via v_exp_f32
}
__device__ __forceinline__ float sigf(float x) {
  return 1.0f / (1.0f + fast_exp(-x));
}
__device__ __forceinline__ float med3(float x, float lo, float hi) {
  // == min(max(x,lo),hi) when lo<=hi (always true for our sorted slots)
  return __builtin_amdgcn_fmed3f(x, lo, hi);
}
__device__ __forceinline__ v2f vfma(v2f a, v2f b, v2f c) {
  return __builtin_elementwise_fma(a, b, c);  // -> v_pk_fma_f32
}

__global__ __launch_bounds__(256) void voronoi_kernel(
    const float* __restrict__ uv, const float* __restrict__ seeds,
    const float* __restrict__ w_raw, const float* __restrict__ h_raw,
    const float* __restrict__ theta, const float* __restrict__ a_raw,
    const float* __restrict__ seed_gates, float* __restrict__ out, int nq) {
  // Pair-transposed per-seed params. For seed pair p (seeds 2p, 2p+1):
  //  quad0: {sx_a, sx_b, sy_a, sy_b}
  //  quad1: {a11_a, a11_b, a12_a, a12_b}   (a11 = c/sc, a12 = sn/sc)
  //  quad2: {a21_a, a21_b, a22_a, a22_b}   (a21 = -sn*sc, a22 = c*sc)
  //  quad3: {h_a, h_b, g_a, g_b}
  __shared__ v4f Pp[(NSEED / 2) * 4];  // 8 KB

  {
    // Per-block prologue: thread s computes seed s params, writes transposed.
    int s = threadIdx.x;
    float sx = seeds[2 * s], sy = seeds[2 * s + 1];
    float th = theta[s];
    float c = cosf(th), sn = sinf(th);
    float sc = expf(a_raw[s]);
    float inv = 1.0f / sc;
    float h = 0.5f + 1.5f * sigf(h_raw[s]);
    float g = sigf(seed_gates[s]);
    float* base = (float*)&Pp[(s >> 1) * 4];
    int b = s & 1;
    base[0 + b] = sx;
    base[2 + b] = sy;
    base[4 + b] = c * inv;
    base[6 + b] = sn * inv;
    base[8 + b] = -sn * sc;
    base[10 + b] = c * sc;
    base[12 + b] = h;
    base[14 + b] = g;
  }
  __syncthreads();

  const int q = blockIdx.x * 256 + threadIdx.x;
  if (q >= nq) return;
  const float2 uvq = ((const float2*)uv)[q];
  const float u = uvq.x, v = uvq.y;
  const v2f uu = {u, u}, vv = {v, v};
  const v2f eps2 = {1e-8f, 1e-8f};

  // ---- Pass A: top-8 on squared distance (sorted ascending) + 2 indices ----
  float dk0 = 3e38f, dk1 = 3e38f, dk2 = 3e38f, dk3 = 3e38f;
  float dk4 = 3e38f, dk5 = 3e38f, dk6 = 3e38f, dk7 = 3e38f;
  int i0 = 0, i1 = 0;

#define INSERT(dval, sidx)                  \
  {                                         \
    float _d = (dval);                      \
    bool c0 = _d < dk0;                     \
    bool c1 = _d < dk1;                     \
    int sh = c0 ? i0 : (sidx);              \
    i1 = c1 ? sh : i1;                      \
    i0 = c0 ? (sidx) : i0;                  \
    dk7 = med3(_d, dk6, dk7);               \
    dk6 = med3(_d, dk5, dk6);               \
    dk5 = med3(_d, dk4, dk5);               \
    dk4 = med3(_d, dk3, dk4);               \
    dk3 = med3(_d, dk2, dk3);               \
    dk2 = med3(_d, dk1, dk2);               \
    dk1 = med3(_d, dk0, dk1);               \
    dk0 = fminf(_d, dk0);                   \
  }

#pragma unroll 4
  for (int p = 0; p < NSEED / 2; ++p) {
    v4f q0 = Pp[4 * p + 0];
    v4f q1 = Pp[4 * p + 1];
    v4f q2 = Pp[4 * p + 2];
    v2f dx = uu - q0.xy, dy = vv - q0.zw;
    v2f xp = vfma(q1.xy, dx, q1.zw * dy);
    v2f yp = vfma(q2.xy, dx, q2.zw * dy);
    v2f d2 = vfma(xp, xp, vfma(yp, yp, eps2));
    INSERT(d2.x, 2 * p);
    INSERT(d2.y, 2 * p + 1);
  }
#undef INSERT

  // sqrt the kept 8 (bitwise-matches pass-B's sqrt of identical d2)
  dk0 = __builtin_amdgcn_sqrtf(dk0);
  dk1 = __builtin_amdgcn_sqrtf(dk1);
  dk2 = __builtin_amdgcn_sqrtf(dk2);
  dk3 = __builtin_amdgcn_sqrtf(dk3);
  dk4 = __builtin_amdgcn_sqrtf(dk4);
  dk5 = __builtin_amdgcn_sqrtf(dk5);
  dk6 = __builtin_amdgcn_sqrtf(dk6);
  dk7 = __builtin_amdgcn_sqrtf(dk7);

  const float d1 = dk0, d3 = dk2;

  // ---- Pass B: full softmax sums with known max (d1) -> no rescaling ----
  const float KB = 72.13475204444817f;  // log2(e)/BETA, BETA=0.02
  const float C1 = d1 * KB;             // exp arg = fma(-KB, d, C1)
  v2f S1 = {0.f, 0.f}, S2 = {0.f, 0.f}, Sh = {0.f, 0.f}, Sg = {0.f, 0.f};
#pragma unroll 4
  for (int p = 0; p < NSEED / 2; ++p) {
    v4f q0 = Pp[4 * p + 0];
    v4f q1 = Pp[4 * p + 1];
    v4f q2 = Pp[4 * p + 2];
    v4f q3 = Pp[4 * p + 3];
    v2f dx = uu - q0.xy, dy = vv - q0.zw;
    v2f xp = vfma(q1.xy, dx, q1.zw * dy);
    v2f yp = vfma(q2.xy, dx, q2.zw * dy);
    v2f d2 = vfma(xp, xp, vfma(yp, yp, eps2));
    float da = __builtin_amdgcn_sqrtf(d2.x);
    float db = __builtin_amdgcn_sqrtf(d2.y);
    v2f e;
    e.x = __builtin_amdgcn_exp2f(fmaf(-KB, da, C1));
    e.y = __builtin_amdgcn_exp2f(fmaf(-KB, db, C1));
    S1 += e;
    S2 = vfma(e, e, S2);
    Sh = vfma(e, q3.xy, Sh);
    Sg = vfma(e, q3.zw, Sg);
  }
  float S1s = S1.x + S1.y;
  float S2s = S2.x + S2.y;
  float Shs = Sh.x + Sh.y;
  float Sgs = Sg.x + Sg.y;

  // ---- Epilogue ----
  // w_pair = W[i0,i1]; W = W_MIN + (wmax-W_MIN)*0.5*(sig(wr01/5)+sig(wr10/5))
  float ax = seeds[2 * i0], ay = seeds[2 * i0 + 1];
  float bx = seeds[2 * i1], by = seeds[2 * i1 + 1];
  float pdx = ax - bx, pdy = ay - by;
  float pd = __builtin_amdgcn_sqrtf(fmaf(pdx, pdx, pdy * pdy));
  float wmax = fmaxf(0.8f * pd, 0.005f + 1e-8f);
  float wr01 = w_raw[(i0 << 8) + i1];
  float wr10 = w_raw[(i1 << 8) + i0];
  float w_pair = 0.005f + (wmax - 0.005f) * 0.5f * (sigf(wr01 * 0.2f) + sigf(wr10 * 0.2f));

  // k_eff = 1/(sum p^2 + EPS) = S1^2 / (S2 + EPS*S1^2)
  float s1sq = S1s * S1s;
  float keff = s1sq / fmaf(1e-8f, s1sq, S2s);
  float bonus = 0.15f * sigf((keff - 3.0f) * (1.0f / 0.35f));

  // triple = 0.15 * exp(-t^1.5), t = (d3-d1)/(w_pair+EPS)
  float t = (d3 - d1) / (w_pair + 1e-8f);
  float t15 = t * __builtin_amdgcn_sqrtf(t);
  float triple = 0.15f * fast_exp(-t15);

  float w_eff = w_pair * (1.0f + bonus + triple);

  // softmin over b_j = 0.5*(dk_j - d1), j=1..7:
  // sdist = b1 - tau*ln(sum_j exp((b1-b_j)/tau)), (b1-b_j)/tau = (dk1-dk_j)*0.5/tau
  const float HT = 360.6737602222409f;  // 0.5/tau * log2(e), tau=0.002
  float acc = 1.0f;  // j=1 term
  acc += __builtin_amdgcn_exp2f((dk1 - dk2) * HT);
  acc += __builtin_amdgcn_exp2f((dk1 - dk3) * HT);
  acc += __builtin_amdgcn_exp2f((dk1 - dk4) * HT);
  acc += __builtin_amdgcn_exp2f((dk1 - dk5) * HT);
  acc += __builtin_amdgcn_exp2f((dk1 - dk6) * HT);
  acc += __builtin_amdgcn_exp2f((dk1 - dk7) * HT);
  float b1 = 0.5f * (dk1 - d1);
  float sdist = b1 - 0.002f * 0.6931471805599453f * __builtin_amdgcn_logf(acc);

  float wall = sigf((0.5f * w_eff - sdist) * 50.0f);  // /BETA
  float invS1 = 1.0f / S1s;
  out[q] = wall * (Sgs * invS1) * (Shs * invS1);
}

extern "C" void kernel_launch(void* const* d_in, const int* in_sizes, int n_in,
                              void* d_out, int out_size, void* d_ws, size_t ws_size,
                              hipStream_t stream) {
  (void)in_sizes;
  (void)n_in;
  (void)d_ws;
  (void)ws_size;
  const float* uv = (const float*)d_in[0];
  const float* seeds = (const float*)d_in[1];
  const float* w_raw = (const float*)d_in[2];
  const float* h_raw = (const float*)d_in[3];
  const float* theta = (const float*)d_in[4];
  const float* a_raw = (const float*)d_in[5];
  const float* gates = (const float*)d_in[6];
  float* out = (float*)d_out;

  int nq = out_size;
  int grid = (nq + 255) / 256;
  voronoi_kernel<<<grid, 256, 0, stream>>>(uv, seeds, w_raw, h_raw, theta,
                                           a_raw, gates, out, nq);
}

// Round 5
// 116.357 us; speedup vs baseline: 1.3472x; 1.0727x over previous
//
#include <hip/hip_runtime.h>

#define NSEED 256

typedef float v2f __attribute__((ext_vector_type(2)));
typedef float v4f __attribute__((ext_vector_type(4)));

__device__ __forceinline__ float fast_exp(float x) {
  return __builtin_amdgcn_exp2f(x * 1.4426950408889634f);  // e^x via v_exp_f32
}
__device__ __forceinline__ float sigf(float x) {
  return 1.0f / (1.0f + fast_exp(-x));
}
__device__ __forceinline__ float med3(float x, float lo, float hi) {
  // == min(max(x,lo),hi) when lo<=hi (always true for our sorted slots)
  return __builtin_amdgcn_fmed3f(x, lo, hi);
}
__device__ __forceinline__ v2f vfma(v2f a, v2f b, v2f c) {
  return __builtin_elementwise_fma(a, b, c);  // -> v_pk_fma_f32
}

__global__ __launch_bounds__(256) void voronoi_kernel(
    const float* __restrict__ uv, const float* __restrict__ seeds,
    const float* __restrict__ w_raw, const float* __restrict__ h_raw,
    const float* __restrict__ theta, const float* __restrict__ a_raw,
    const float* __restrict__ seed_gates, float* __restrict__ out, int nq) {
  // Pair-transposed per-seed params. For seed pair p (seeds 2p, 2p+1):
  //  quad0: {sx_a, sx_b, sy_a, sy_b}
  //  quad1: {a11_a, a11_b, a12_a, a12_b}   (a11 = c/sc, a12 = sn/sc)
  //  quad2: {a21_a, a21_b, a22_a, a22_b}   (a21 = -sn*sc, a22 = c*sc)
  //  quad3: {h_a, h_b, g_a, g_b}
  __shared__ v4f Pp[(NSEED / 2) * 4];  // 8 KB

  {
    int s = threadIdx.x;
    float sx = seeds[2 * s], sy = seeds[2 * s + 1];
    float th = theta[s];
    float c = cosf(th), sn = sinf(th);
    float sc = expf(a_raw[s]);
    float inv = 1.0f / sc;
    float h = 0.5f + 1.5f * sigf(h_raw[s]);
    float g = sigf(seed_gates[s]);
    float* base = (float*)&Pp[(s >> 1) * 4];
    int b = s & 1;
    base[0 + b] = sx;
    base[2 + b] = sy;
    base[4 + b] = c * inv;
    base[6 + b] = sn * inv;
    base[8 + b] = -sn * sc;
    base[10 + b] = c * sc;
    base[12 + b] = h;
    base[14 + b] = g;
  }
  __syncthreads();

  // Two lanes per query: lane parity picks half of the seed set.
  const int t = blockIdx.x * 256 + threadIdx.x;
  const int q = t >> 1;
  const int par = t & 1;
  if (q >= nq) return;
  const float2 uvq = ((const float2*)uv)[q];
  const v2f uu = {uvq.x, uvq.x}, vv = {uvq.y, uvq.y};
  const v2f eps2 = {1e-8f, 1e-8f};
  const float NK = -72.13475204444817f;  // -log2(e)/BETA, BETA=0.02

  float dk0 = 3e38f, dk1 = 3e38f, dk2 = 3e38f, dk3 = 3e38f;
  float dk4 = 3e38f, dk5 = 3e38f, dk6 = 3e38f, dk7 = 3e38f;
  int i0 = 0, i1 = 0;
  v2f S1 = {0.f, 0.f}, S2 = {0.f, 0.f}, Sh = {0.f, 0.f}, Sg = {0.f, 0.f};

  // Exact d^2 comparisons (strict <, old dk0/dk1) reproduce top_k's
  // lowest-index tie-break; no key masking (round-4 lesson: masking widened
  // tie classes to 2^-15 rel -> i2/i3 flips -> wrong W[i1,i2]).
#define INS(x, sidx)             \
  {                              \
    float _d = (x);              \
    bool c0 = _d < dk0;          \
    bool c1 = _d < dk1;          \
    int sh = c0 ? i0 : (sidx);   \
    i1 = c1 ? sh : i1;           \
    i0 = c0 ? (sidx) : i0;       \
    dk7 = med3(_d, dk6, dk7);    \
    dk6 = med3(_d, dk5, dk6);    \
    dk5 = med3(_d, dk4, dk5);    \
    dk4 = med3(_d, dk3, dk4);    \
    dk3 = med3(_d, dk2, dk3);    \
    dk2 = med3(_d, dk1, dk2);    \
    dk1 = med3(_d, dk0, dk1);    \
    dk0 = fminf(_d, dk0);        \
  }

  const int pbase = par * 64;  // 64 seed-pairs per lane
#pragma unroll 4
  for (int k = 0; k < 64; ++k) {
    int p = pbase + k;
    v4f q0 = Pp[4 * p + 0];
    v4f q1 = Pp[4 * p + 1];
    v4f q2 = Pp[4 * p + 2];
    v4f q3 = Pp[4 * p + 3];
    v2f dx = uu - q0.xy, dy = vv - q0.zw;
    v2f xp = vfma(q1.xy, dx, q1.zw * dy);
    v2f yp = vfma(q2.xy, dx, q2.zw * dy);
    v2f d2 = vfma(xp, xp, vfma(yp, yp, eps2));
    INS(d2.x, 2 * p);
    INS(d2.y, 2 * p + 1);
    // unshifted softmax terms 2^(-K*d): all consumers are scale-invariant
    float da = __builtin_amdgcn_sqrtf(d2.x);
    float db = __builtin_amdgcn_sqrtf(d2.y);
    v2f e;
    e.x = __builtin_amdgcn_exp2f(da * NK);
    e.y = __builtin_amdgcn_exp2f(db * NK);
    S1 += e;
    S2 = vfma(e, e, S2);
    Sh = vfma(e, q3.xy, Sh);
    Sg = vfma(e, q3.zw, Sg);
  }
#undef INS

  // ---- cross-lane merge of two sorted-8 value lists (both lanes) ----
  float b0 = __shfl_xor(dk0, 1), b1 = __shfl_xor(dk1, 1);
  float b2 = __shfl_xor(dk2, 1), b3 = __shfl_xor(dk3, 1);
  float b4 = __shfl_xor(dk4, 1), b5 = __shfl_xor(dk5, 1);
  float b6 = __shfl_xor(dk6, 1), b7 = __shfl_xor(dk7, 1);
  // ---- top-2 index merge (correct on lane par==0, the writer; there
  // "self" holds seeds 0..127 so ties prefer self = lower index) ----
  int j0 = __shfl_xor(i0, 1), j1 = __shfl_xor(i1, 1);
  bool aw = b0 < dk0;  // partner strictly nearer
  int I0 = aw ? j0 : i0;
  float ec1 = aw ? dk0 : dk1;
  int ic1 = aw ? i0 : i1;
  float ec2 = aw ? b1 : b0;
  int ic2 = aw ? j1 : j0;
  int I1 = (ec2 < ec1) ? ic2 : ic1;

  // half-cleaner: lowest 8 of the 16, forms a bitonic sequence
  float m0 = fminf(dk0, b7), m1 = fminf(dk1, b6);
  float m2 = fminf(dk2, b5), m3 = fminf(dk3, b4);
  float m4 = fminf(dk4, b3), m5 = fminf(dk5, b2);
  float m6 = fminf(dk6, b1), m7 = fminf(dk7, b0);
#define CE(a, b)             \
  {                          \
    float _lo = fminf(a, b); \
    float _hi = fmaxf(a, b); \
    a = _lo;                 \
    b = _hi;                 \
  }
  CE(m0, m4) CE(m1, m5) CE(m2, m6) CE(m3, m7)
  CE(m0, m2) CE(m1, m3) CE(m4, m6) CE(m5, m7)
  CE(m0, m1) CE(m2, m3) CE(m4, m5) CE(m6, m7)
#undef CE

  dk0 = __builtin_amdgcn_sqrtf(m0);
  dk1 = __builtin_amdgcn_sqrtf(m1);
  dk2 = __builtin_amdgcn_sqrtf(m2);
  dk3 = __builtin_amdgcn_sqrtf(m3);
  dk4 = __builtin_amdgcn_sqrtf(m4);
  dk5 = __builtin_amdgcn_sqrtf(m5);
  dk6 = __builtin_amdgcn_sqrtf(m6);
  dk7 = __builtin_amdgcn_sqrtf(m7);
  const float d1 = dk0, d3 = dk2;

  // combine softmax partials across the lane pair
  float S1s = S1.x + S1.y;
  float S2s = S2.x + S2.y;
  float Shs = Sh.x + Sh.y;
  float Sgs = Sg.x + Sg.y;
  S1s += __shfl_xor(S1s, 1);
  S2s += __shfl_xor(S2s, 1);
  Shs += __shfl_xor(Shs, 1);
  Sgs += __shfl_xor(Sgs, 1);

  // ---- Epilogue ----
  float ax = seeds[2 * I0], ay = seeds[2 * I0 + 1];
  float bx = seeds[2 * I1], by = seeds[2 * I1 + 1];
  float pdx = ax - bx, pdy = ay - by;
  float pd = __builtin_amdgcn_sqrtf(fmaf(pdx, pdx, pdy * pdy));
  float wmax = fmaxf(0.8f * pd, 0.005f + 1e-8f);
  float wr01 = w_raw[(I0 << 8) + I1];
  float wr10 = w_raw[(I1 << 8) + I0];
  float w_pair = 0.005f + (wmax - 0.005f) * 0.5f * (sigf(wr01 * 0.2f) + sigf(wr10 * 0.2f));

  // k_eff = 1/(sum p^2 + EPS) = S1^2/(S2 + EPS*S1^2)  (shift-invariant)
  float s1sq = S1s * S1s;
  float keff = s1sq / fmaf(1e-8f, s1sq, S2s);
  float bonus = 0.15f * sigf((keff - 3.0f) * (1.0f / 0.35f));

  float tt = (d3 - d1) / (w_pair + 1e-8f);
  float t15 = tt * __builtin_amdgcn_sqrtf(tt);
  float triple = 0.15f * fast_exp(-t15);

  float w_eff = w_pair * (1.0f + bonus + triple);

  const float HT = 360.6737602222409f;  // 0.5/tau * log2(e), tau=0.002
  float acc = 1.0f;
  acc += __builtin_amdgcn_exp2f((dk1 - dk2) * HT);
  acc += __builtin_amdgcn_exp2f((dk1 - dk3) * HT);
  acc += __builtin_amdgcn_exp2f((dk1 - dk4) * HT);
  acc += __builtin_amdgcn_exp2f((dk1 - dk5) * HT);
  acc += __builtin_amdgcn_exp2f((dk1 - dk6) * HT);
  acc += __builtin_amdgcn_exp2f((dk1 - dk7) * HT);
  float b1s = 0.5f * (dk1 - d1);
  float sdist = b1s - 0.002f * 0.6931471805599453f * __builtin_amdgcn_logf(acc);

  float wall = sigf((0.5f * w_eff - sdist) * 50.0f);
  float invS1 = 1.0f / S1s;
  if (par == 0) out[q] = wall * (Sgs * invS1) * (Shs * invS1);
}

extern "C" void kernel_launch(void* const* d_in, const int* in_sizes, int n_in,
                              void* d_out, int out_size, void* d_ws, size_t ws_size,
                              hipStream_t stream) {
  (void)in_sizes;
  (void)n_in;
  (void)d_ws;
  (void)ws_size;
  const float* uv = (const float*)d_in[0];
  const float* seeds = (const float*)d_in[1];
  const float* w_raw = (const float*)d_in[2];
  const float* h_raw = (const float*)d_in[3];
  const float* theta = (const float*)d_in[4];
  const float* a_raw = (const float*)d_in[5];
  const float* gates = (const float*)d_in[6];
  float* out = (float*)d_out;

  int nq = out_size;
  long long threads = 2LL * nq;  // 2 lanes per query
  int grid = (int)((threads + 255) / 256);
  voronoi_kernel<<<grid, 256, 0, stream>>>(uv, seeds, w_raw, h_raw, theta,
                                           a_raw, gates, out, nq);
}

// Round 6
// 114.971 us; speedup vs baseline: 1.3634x; 1.0121x over previous
//
#include <hip/hip_runtime.h>

#define NSEED 256
// floats per half-table: 64 pairs * 16 floats = 1024, +16 skew pad so the
// two halves' reads land on disjoint bank groups (4160 B / 4 % 32 = bank 16).
#define HALF_STRIDE 1040

typedef float v2f __attribute__((ext_vector_type(2)));
typedef float v4f __attribute__((ext_vector_type(4)));

__device__ __forceinline__ float fast_exp(float x) {
  return __builtin_amdgcn_exp2f(x * 1.4426950408889634f);  // e^x via v_exp_f32
}
__device__ __forceinline__ float sigf(float x) {
  return 1.0f / (1.0f + fast_exp(-x));
}
__device__ __forceinline__ float med3(float x, float lo, float hi) {
  // == min(max(x,lo),hi) when lo<=hi (always true for our sorted slots)
  return __builtin_amdgcn_fmed3f(x, lo, hi);
}
__device__ __forceinline__ v2f vfma(v2f a, v2f b, v2f c) {
  return __builtin_elementwise_fma(a, b, c);  // -> v_pk_fma_f32
}

__global__ __launch_bounds__(256) void voronoi_kernel(
    const float* __restrict__ uv, const float* __restrict__ seeds,
    const float* __restrict__ w_raw, const float* __restrict__ h_raw,
    const float* __restrict__ theta, const float* __restrict__ a_raw,
    const float* __restrict__ seed_gates, float* __restrict__ out, int nq) {
  // Pair-transposed per-seed params, split into two bank-skewed half-tables.
  // For seed pair p: quad0 {sx_a,sx_b,sy_a,sy_b}, quad1 {a11_a,a11_b,a12_a,
  // a12_b}, quad2 {a21_a,a21_b,a22_a,a22_b}, quad3 {h_a,h_b,g_a,g_b}.
  __shared__ float Ppf[2 * HALF_STRIDE];  // 8320 B

  {
    int s = threadIdx.x;  // one thread per seed
    float sx = seeds[2 * s], sy = seeds[2 * s + 1];
    float th = theta[s];
    float c = cosf(th), sn = sinf(th);
    float sc = expf(a_raw[s]);
    float inv = 1.0f / sc;
    float h = 0.5f + 1.5f * sigf(h_raw[s]);
    float g = sigf(seed_gates[s]);
    int pair = s >> 1, b = s & 1;
    int half = pair >> 6, lp = pair & 63;
    float* base = Ppf + half * HALF_STRIDE + lp * 16;
    base[0 + b] = sx;
    base[2 + b] = sy;
    base[4 + b] = c * inv;
    base[6 + b] = sn * inv;
    base[8 + b] = -sn * sc;
    base[10 + b] = c * sc;
    base[12 + b] = h;
    base[14 + b] = g;
  }
  __syncthreads();

  // Two lanes per query: lane parity picks a half of the seed set.
  const int t = blockIdx.x * 256 + threadIdx.x;
  const int q = t >> 1;
  const int par = t & 1;
  if (q >= nq) return;
  const float2 uvq = ((const float2*)uv)[q];
  const v2f uu = {uvq.x, uvq.x}, vv = {uvq.y, uvq.y};
  const v2f eps2 = {1e-8f, 1e-8f};
  const float NK = -72.13475204444817f;  // -log2(e)/BETA, BETA=0.02

  float dk0 = 3e38f, dk1 = 3e38f, dk2 = 3e38f, dk3 = 3e38f;
  float dk4 = 3e38f, dk5 = 3e38f, dk6 = 3e38f, dk7 = 3e38f;
  int i0 = 0, i1 = 0;  // k-local (0..127); par<<7 OR'd in after the loop
  v2f S1 = {0.f, 0.f}, S2 = {0.f, 0.f}, Sh = {0.f, 0.f}, Sg = {0.f, 0.f};

  // Exact d^2 comparisons (strict <, old dk0/dk1) reproduce top_k's
  // lowest-index tie-break (round-4 lesson: no key masking).
#define INS(x, sidx)             \
  {                              \
    float _d = (x);              \
    bool c0 = _d < dk0;          \
    bool c1 = _d < dk1;          \
    int sh = c0 ? i0 : (sidx);   \
    i1 = c1 ? sh : i1;           \
    i0 = c0 ? (sidx) : i0;       \
    dk7 = med3(_d, dk6, dk7);    \
    dk6 = med3(_d, dk5, dk6);    \
    dk5 = med3(_d, dk4, dk5);    \
    dk4 = med3(_d, dk3, dk4);    \
    dk3 = med3(_d, dk2, dk3);    \
    dk2 = med3(_d, dk1, dk2);    \
    dk1 = med3(_d, dk0, dk1);    \
    dk0 = fminf(_d, dk0);        \
  }

  const v4f* __restrict__ PF = (const v4f*)(Ppf + par * HALF_STRIDE);
#pragma unroll 8
  for (int k = 0; k < 64; ++k) {
    v4f q0 = PF[4 * k + 0];
    v4f q1 = PF[4 * k + 1];
    v4f q2 = PF[4 * k + 2];
    v4f q3 = PF[4 * k + 3];
    v2f dx = uu - q0.xy, dy = vv - q0.zw;
    v2f xp = vfma(q1.xy, dx, q1.zw * dy);
    v2f yp = vfma(q2.xy, dx, q2.zw * dy);
    v2f d2 = vfma(xp, xp, vfma(yp, yp, eps2));
    INS(d2.x, 2 * k);      // compile-time sidx under unroll
    INS(d2.y, 2 * k + 1);
    // unshifted softmax terms 2^(-K*d): all consumers are scale-invariant
    float da = __builtin_amdgcn_sqrtf(d2.x);
    float db = __builtin_amdgcn_sqrtf(d2.y);
    v2f e;
    e.x = __builtin_amdgcn_exp2f(da * NK);
    e.y = __builtin_amdgcn_exp2f(db * NK);
    S1 += e;
    S2 = vfma(e, e, S2);
    Sh = vfma(e, q3.xy, Sh);
    Sg = vfma(e, q3.zw, Sg);
  }
#undef INS

  i0 |= par << 7;  // globalize seed indices
  i1 |= par << 7;

  // ---- cross-lane merge of two sorted-8 value lists (both lanes) ----
  float b0 = __shfl_xor(dk0, 1), b1 = __shfl_xor(dk1, 1);
  float b2 = __shfl_xor(dk2, 1), b3 = __shfl_xor(dk3, 1);
  float b4 = __shfl_xor(dk4, 1), b5 = __shfl_xor(dk5, 1);
  float b6 = __shfl_xor(dk6, 1), b7 = __shfl_xor(dk7, 1);
  // ---- top-2 index merge (correct on lane par==0, the writer; there
  // "self" holds seeds 0..127 so strict-< ties prefer self = lower index)
  int j0 = __shfl_xor(i0, 1), j1 = __shfl_xor(i1, 1);
  bool aw = b0 < dk0;  // partner strictly nearer
  int I0 = aw ? j0 : i0;
  float ec1 = aw ? dk0 : dk1;
  int ic1 = aw ? i0 : i1;
  float ec2 = aw ? b1 : b0;
  int ic2 = aw ? j1 : j0;
  int I1 = (ec2 < ec1) ? ic2 : ic1;

  // half-cleaner: lowest 8 of the 16, forms a bitonic sequence
  float m0 = fminf(dk0, b7), m1 = fminf(dk1, b6);
  float m2 = fminf(dk2, b5), m3 = fminf(dk3, b4);
  float m4 = fminf(dk4, b3), m5 = fminf(dk5, b2);
  float m6 = fminf(dk6, b1), m7 = fminf(dk7, b0);
#define CE(a, b)             \
  {                          \
    float _lo = fminf(a, b); \
    float _hi = fmaxf(a, b); \
    a = _lo;                 \
    b = _hi;                 \
  }
  CE(m0, m4) CE(m1, m5) CE(m2, m6) CE(m3, m7)
  CE(m0, m2) CE(m1, m3) CE(m4, m6) CE(m5, m7)
  CE(m0, m1) CE(m2, m3) CE(m4, m5) CE(m6, m7)
#undef CE

  dk0 = __builtin_amdgcn_sqrtf(m0);
  dk1 = __builtin_amdgcn_sqrtf(m1);
  dk2 = __builtin_amdgcn_sqrtf(m2);
  dk3 = __builtin_amdgcn_sqrtf(m3);
  dk4 = __builtin_amdgcn_sqrtf(m4);
  dk5 = __builtin_amdgcn_sqrtf(m5);
  dk6 = __builtin_amdgcn_sqrtf(m6);
  dk7 = __builtin_amdgcn_sqrtf(m7);
  const float d1 = dk0, d3 = dk2;

  // combine softmax partials across the lane pair
  float S1s = S1.x + S1.y;
  float S2s = S2.x + S2.y;
  float Shs = Sh.x + Sh.y;
  float Sgs = Sg.x + Sg.y;
  S1s += __shfl_xor(S1s, 1);
  S2s += __shfl_xor(S2s, 1);
  Shs += __shfl_xor(Shs, 1);
  Sgs += __shfl_xor(Sgs, 1);

  // ---- Epilogue ----
  float ax = seeds[2 * I0], ay = seeds[2 * I0 + 1];
  float bx = seeds[2 * I1], by = seeds[2 * I1 + 1];
  float pdx = ax - bx, pdy = ay - by;
  float pd = __builtin_amdgcn_sqrtf(fmaf(pdx, pdx, pdy * pdy));
  float wmax = fmaxf(0.8f * pd, 0.005f + 1e-8f);
  float wr01 = w_raw[(I0 << 8) + I1];
  float wr10 = w_raw[(I1 << 8) + I0];
  float w_pair = 0.005f + (wmax - 0.005f) * 0.5f * (sigf(wr01 * 0.2f) + sigf(wr10 * 0.2f));

  // k_eff = 1/(sum p^2 + EPS) = S1^2/(S2 + EPS*S1^2)  (shift-invariant)
  float s1sq = S1s * S1s;
  float keff = s1sq / fmaf(1e-8f, s1sq, S2s);
  float bonus = 0.15f * sigf((keff - 3.0f) * (1.0f / 0.35f));

  float tt = (d3 - d1) / (w_pair + 1e-8f);
  float t15 = tt * __builtin_amdgcn_sqrtf(tt);
  float triple = 0.15f * fast_exp(-t15);

  float w_eff = w_pair * (1.0f + bonus + triple);

  const float HT = 360.6737602222409f;  // 0.5/tau * log2(e), tau=0.002
  float acc = 1.0f;
  acc += __builtin_amdgcn_exp2f((dk1 - dk2) * HT);
  acc += __builtin_amdgcn_exp2f((dk1 - dk3) * HT);
  acc += __builtin_amdgcn_exp2f((dk1 - dk4) * HT);
  acc += __builtin_amdgcn_exp2f((dk1 - dk5) * HT);
  acc += __builtin_amdgcn_exp2f((dk1 - dk6) * HT);
  acc += __builtin_amdgcn_exp2f((dk1 - dk7) * HT);
  float b1s = 0.5f * (dk1 - d1);
  float sdist = b1s - 0.002f * 0.6931471805599453f * __builtin_amdgcn_logf(acc);

  float wall = sigf((0.5f * w_eff - sdist) * 50.0f);
  float invS1 = 1.0f / S1s;
  if (par == 0) out[q] = wall * (Sgs * invS1) * (Shs * invS1);
}

extern "C" void kernel_launch(void* const* d_in, const int* in_sizes, int n_in,
                              void* d_out, int out_size, void* d_ws, size_t ws_size,
                              hipStream_t stream) {
  (void)in_sizes;
  (void)n_in;
  (void)d_ws;
  (void)ws_size;
  const float* uv = (const float*)d_in[0];
  const float* seeds = (const float*)d_in[1];
  const float* w_raw = (const float*)d_in[2];
  const float* h_raw = (const float*)d_in[3];
  const float* theta = (const float*)d_in[4];
  const float* a_raw = (const float*)d_in[5];
  const float* gates = (const float*)d_in[6];
  float* out = (float*)d_out;

  int nq = out_size;
  long long threads = 2LL * nq;  // 2 lanes per query
  int grid = (int)((threads + 255) / 256);
  voronoi_kernel<<<grid, 256, 0, stream>>>(uv, seeds, w_raw, h_raw, theta,
                                           a_raw, gates, out, nq);
}